// Round 20
// baseline (361.608 us; speedup 1.0000x reference)
//
#include <hip/hip_runtime.h>
#include <hip/hip_bf16.h>
#include <stdint.h>

#define TOKS 2048
#define DHID 2048
#define NEXP 8
#define FR 1408
#define FS 2816
#define RSCALE 2.5f

// gemm1: shared 16mt*22nt=352 first, routed <=39*11=429 -> 784=8*98
#define G1_SH 352
#define G1_GRID 784
#define G1_Q (G1_GRID / 8)
// gemm2 (BN=128): shared 16*16=256, routed <=39*16=624 -> 880=8*110
#define G2_SH 256
#define G2_GRID 880
#define G2_Q (G2_GRID / 8)
// weight image counts (64k x 128n panels of 16KB)
#define NIMG_WG 2816   // 8e * 11nt * 32kt
#define NIMG_WD 2816   // 8e * 16nt * 22kt
#define NIMG_SG 704    // 22nt * 32kt
#define NIMG_SD 704    // 16nt * 44kt
// rwimg converts only gate/up (down converts inside gemm1 dispatch)
#define RW_GRID (512 + NIMG_WG * 2 + NIMG_SG * 2)   // 7552
#define G1_CONV (NIMG_WD + NIMG_SD)                 // 3520
#define G1_FULL (G1_GRID + G1_CONV)                 // 4304

typedef float f32x4 __attribute__((ext_vector_type(4)));
typedef short s16x8 __attribute__((ext_vector_type(8)));

__device__ __forceinline__ ushort f2bf(float f) {
  union { __hip_bfloat16 b; ushort u; } v;
  v.b = __float2bfloat16(f);
  return v.u;
}

__device__ __forceinline__ void gload16(const void* g, void* l) {
  __builtin_amdgcn_global_load_lds(
      (const __attribute__((address_space(1))) unsigned int*)g,
      (__attribute__((address_space(3))) unsigned int*)l, 16, 0, 0);
}

// shared conversion body: one 64k x 128n panel fp32[K][N] -> swizzled bf16 image
__device__ __forceinline__ void conv_panel(
    const float* __restrict__ src, ushort* __restrict__ dst,
    int N, int nt, int kt, char* smem) {
  float (*lds)[133] = (float(*)[133])smem;
  const int tid = threadIdx.x;
#pragma unroll
  for (int j = 0; j < 8; ++j) {
    const int idx = j * 256 + tid;
    const int row = idx >> 5, c4 = (idx & 31) << 2;
    const float4 v = *(const float4*)(src + (size_t)(kt * 64 + row) * N + nt * 128 + c4);
    lds[row][c4] = v.x; lds[row][c4 + 1] = v.y; lds[row][c4 + 2] = v.z; lds[row][c4 + 3] = v.w;
  }
  __syncthreads();
#pragma unroll
  for (int s = 0; s < 4; ++s) {
    const int sid = s * 256 + tid;
    const int col = sid >> 3, ks = sid & 7;
    ushort tmp[8];
#pragma unroll
    for (int j = 0; j < 8; ++j) tmp[j] = f2bf(lds[ks * 8 + j][col]);
    *(s16x8*)((char*)dst + col * 128 + ((ks ^ (col & 7)) * 16)) = *(const s16x8*)&tmp[0];
  }
}

// ---------------- fused: router (blocks 0..511) + gate/up weight->image ----------------
__global__ __launch_bounds__(256) void k_rwimg(
    const float* __restrict__ x, const float* __restrict__ wr,
    ushort* __restrict__ xb, int* __restrict__ top_e, float* __restrict__ top_w,
    const float* __restrict__ wg, const float* __restrict__ wu,
    const float* __restrict__ wsg, const float* __restrict__ wsu,
    ushort* __restrict__ ig, ushort* __restrict__ iu,
    ushort* __restrict__ isg, ushort* __restrict__ isu) {
  __shared__ char smem[34048];
  if (blockIdx.x < 512) {
    const int wid = threadIdx.x >> 6, lane = threadIdx.x & 63;
    const int t = blockIdx.x * 4 + wid;
    const float* xrow = x + (size_t)t * DHID;
    float acc[NEXP];
#pragma unroll
    for (int e = 0; e < NEXP; ++e) acc[e] = 0.f;
#pragma unroll 4
    for (int j = 0; j < DHID / 64; ++j) {
      const int k = j * 64 + lane;
      const float xv = xrow[k];
      xb[(size_t)t * DHID + k] = f2bf(xv);
      const float4 w0 = *(const float4*)(wr + (size_t)k * 8);
      const float4 w1 = *(const float4*)(wr + (size_t)k * 8 + 4);
      acc[0] += xv * w0.x; acc[1] += xv * w0.y; acc[2] += xv * w0.z; acc[3] += xv * w0.w;
      acc[4] += xv * w1.x; acc[5] += xv * w1.y; acc[6] += xv * w1.z; acc[7] += xv * w1.w;
    }
#pragma unroll
    for (int e = 0; e < NEXP; ++e) {
#pragma unroll
      for (int off = 32; off; off >>= 1) acc[e] += __shfl_xor(acc[e], off);
    }
    if (lane == 0) {
      int i1 = 0;
#pragma unroll
      for (int e = 1; e < NEXP; ++e) if (acc[e] > acc[i1]) i1 = e;
      int i2 = (i1 == 0) ? 1 : 0;
#pragma unroll
      for (int e = 0; e < NEXP; ++e) if (e != i1 && acc[e] > acc[i2]) i2 = e;
      const float w1 = 1.f / (1.f + expf(acc[i2] - acc[i1]));
      top_e[2 * t] = i1; top_e[2 * t + 1] = i2;
      top_w[2 * t] = w1; top_w[2 * t + 1] = 1.f - w1;
    }
    return;
  }
  int id = blockIdx.x - 512;
  const float* src; ushort* dst; int N, ntT, ktT;
  if (id < NIMG_WG)                   { src = wg;  dst = ig;  N = FR; ntT = 11; ktT = 32; }
  else if ((id -= NIMG_WG) < NIMG_WG) { src = wu;  dst = iu;  N = FR; ntT = 11; ktT = 32; }
  else if ((id -= NIMG_WG) < NIMG_SG) { src = wsg; dst = isg; N = FS; ntT = 22; ktT = 32; }
  else { id -= NIMG_SG;                 src = wsu; dst = isu; N = FS; ntT = 22; ktT = 32; }
  const int per_e = ntT * ktT;
  const int e = id / per_e, rem = id % per_e;
  const int nt = rem / ktT, kt = rem % ktT;
  const int K = ktT * 64;
  conv_panel(src + (size_t)e * K * N, dst + (size_t)id * 8192, N, nt, kt, smem);
}

// ---------------- per-expert token lists + m-tile work list ----------------
__global__ __launch_bounds__(256) void k_lists(
    const int* __restrict__ top_e, const float* __restrict__ top_w,
    int* __restrict__ offs, int* __restrict__ ptok, float* __restrict__ pw,
    int* __restrict__ meta, int* __restrict__ mtl) {
  __shared__ int cnt[NEXP], fill[NEXP], loff[NEXP + 1];
  const int tid = threadIdx.x;
  if (tid < NEXP) { cnt[tid] = 0; fill[tid] = 0; }
  __syncthreads();
  for (int p = tid; p < 2 * TOKS; p += 256) atomicAdd(&cnt[top_e[p]], 1);
  __syncthreads();
  if (tid == 0) {
    loff[0] = 0;
    for (int e = 0; e < NEXP; ++e) loff[e + 1] = loff[e] + cnt[e];
    int n = 0;
    for (int e = 0; e < NEXP; ++e)
      for (int m = 0; m * 128 < cnt[e]; ++m) mtl[n++] = (e << 8) | m;
    meta[0] = n;
  }
  __syncthreads();
  for (int p = tid; p < 2 * TOKS; p += 256) {
    const int e = top_e[p];
    const int pos = loff[e] + atomicAdd(&fill[e], 1);
    ptok[pos] = p >> 1;
    pw[pos] = top_w[p];
  }
  if (tid < NEXP + 1) offs[tid] = loff[tid];
}

// ---------------- GEMM1 + trailing down-weight conversion blocks ----------------
__global__ __launch_bounds__(256, 2) void k_gemm1i(
    const ushort* __restrict__ xb,
    const ushort* __restrict__ ig, const ushort* __restrict__ iu, ushort* __restrict__ Hr,
    const ushort* __restrict__ isg, const ushort* __restrict__ isu, ushort* __restrict__ Hs,
    const int* __restrict__ offs, const int* __restrict__ ptok,
    const int* __restrict__ meta, const int* __restrict__ mtl,
    const float* __restrict__ wd, const float* __restrict__ wsd,
    ushort* __restrict__ id_, ushort* __restrict__ isd) {
  __shared__ char smem[81920];  // gemm1: A 16K | buf0 g+u 32K | buf1 g+u 32K; conv aliases front
  if (blockIdx.x >= G1_GRID) {
    int cid = blockIdx.x - G1_GRID;
    const float* src; ushort* dst; int ntT, ktT;
    if (cid < NIMG_WD) { src = wd; dst = id_; ntT = 16; ktT = 22; }
    else { cid -= NIMG_WD; src = wsd; dst = isd; ntT = 16; ktT = 44; }
    const int per_e = ntT * ktT;
    const int e = cid / per_e, rem = cid % per_e;
    const int nt = rem / ktT, kt = rem % ktT;
    const int K = ktT * 64;
    conv_panel(src + (size_t)e * K * DHID, dst + (size_t)cid * 8192, DHID, nt, kt, smem);
    return;
  }
  constexpr int KT = DHID / 64;
  const int swz = (blockIdx.x & 7) * G1_Q + (blockIdx.x >> 3);
  int mt, nt, N, base, count;
  const char *imgG, *imgU;
  ushort* H;
  bool gather;
  if (swz < G1_SH) {
    mt = swz & 15; nt = swz >> 4;
    base = 0; count = TOKS; N = FS;
    imgG = (const char*)isg + (size_t)(nt * 32) * 16384;
    imgU = (const char*)isu + (size_t)(nt * 32) * 16384;
    H = Hs; gather = false;
  } else {
    const int r = swz - G1_SH;
    const int n_mt = meta[0];
    if (r >= n_mt * 11) return;
    const int tile = mtl[r / 11];
    nt = r % 11;
    const int e = tile >> 8; mt = tile & 255;
    base = offs[e]; count = offs[e + 1] - base; N = FR;
    imgG = (const char*)ig + (size_t)((e * 11 + nt) * 32) * 16384;
    imgU = (const char*)iu + (size_t)((e * 11 + nt) * 32) * 16384;
    H = Hr; gather = true;
  }

  const int tid = threadIdx.x, lane = tid & 63, wid = tid >> 6;
  const int wm = wid >> 1, wn = wid & 1;

  const int aj = tid & 7;
  const ushort* aptr[4];
  uint32_t alds[4];
#pragma unroll
  for (int i = 0; i < 4; ++i) {
    const int row = i * 32 + (tid >> 3);
    const int gr = mt * 128 + row;
    const int arow = gather ? ptok[base + (gr < count ? gr : count - 1)] : gr;
    aptr[i] = xb + (size_t)arow * DHID + aj * 8;
    alds[i] = (uint32_t)(row * 128 + ((aj ^ (row & 7)) * 16));
  }

  const f32x4 fz = {0.f, 0.f, 0.f, 0.f};
  f32x4 accg[4][4], accu[4][4];
#pragma unroll
  for (int mi = 0; mi < 4; ++mi)
#pragma unroll
    for (int ni = 0; ni < 4; ++ni) { accg[mi][ni] = fz; accu[mi][ni] = fz; }

  s16x8 areg[4];
#pragma unroll
  for (int i = 0; i < 4; ++i) areg[i] = *(const s16x8*)(aptr[i]);
#pragma unroll
  for (int i = 0; i < 4; ++i) {
    const int o = (i * 4 + wid) * 1024 + lane * 16;
    gload16(imgG + o, smem + 16384 + o);
    gload16(imgU + o, smem + 32768 + o);
  }

  for (int t = 0; t < KT; ++t) {
    const int bufo = 16384 + (t & 1) * 32768;
#pragma unroll
    for (int i = 0; i < 4; ++i) *(s16x8*)(smem + alds[i]) = areg[i];
    __builtin_amdgcn_sched_barrier(0);
    if (t + 1 < KT) {
#pragma unroll
      for (int i = 0; i < 4; ++i) areg[i] = *(const s16x8*)(aptr[i] + (t + 1) * 64);
      const int nbufo = 16384 + ((t + 1) & 1) * 32768;
      const char* gG = imgG + (size_t)(t + 1) * 16384;
      const char* gU = imgU + (size_t)(t + 1) * 16384;
#pragma unroll
      for (int i = 0; i < 4; ++i) {
        const int o = (i * 4 + wid) * 1024 + lane * 16;
        gload16(gG + o, smem + nbufo + o);
        gload16(gU + o, smem + nbufo + 16384 + o);
      }
      asm volatile("s_waitcnt vmcnt(12) lgkmcnt(0)" ::: "memory");
    } else {
      asm volatile("s_waitcnt vmcnt(0) lgkmcnt(0)" ::: "memory");
    }
    __builtin_amdgcn_sched_barrier(0);
    __builtin_amdgcn_s_barrier();
    __builtin_amdgcn_sched_barrier(0);
    __builtin_amdgcn_s_setprio(1);
#pragma unroll
    for (int kk = 0; kk < 64; kk += 32) {
      s16x8 af[4];
#pragma unroll
      for (int mi = 0; mi < 4; ++mi) {
        const int row = wm * 64 + mi * 16 + (lane & 15);
        const int slot = (kk >> 3) + (lane >> 4);
        af[mi] = *(const s16x8*)(smem + row * 128 + ((slot ^ (row & 7)) * 16));
      }
#pragma unroll
      for (int ni = 0; ni < 4; ++ni) {
        const int colg = wn * 64 + ni * 16 + (lane & 15);
        const int slot = (kk >> 3) + (lane >> 4);
        const uint32_t boff = (uint32_t)(colg * 128 + ((slot ^ (colg & 7)) * 16));
        const s16x8 bg = *(const s16x8*)(smem + bufo + boff);
        const s16x8 bu = *(const s16x8*)(smem + bufo + 16384 + boff);
#pragma unroll
        for (int mi = 0; mi < 4; ++mi) {
          accg[mi][ni] = __builtin_amdgcn_mfma_f32_16x16x32_bf16(af[mi], bg, accg[mi][ni], 0, 0, 0);
          accu[mi][ni] = __builtin_amdgcn_mfma_f32_16x16x32_bf16(af[mi], bu, accu[mi][ni], 0, 0, 0);
        }
      }
    }
    __builtin_amdgcn_s_setprio(0);
    __builtin_amdgcn_s_barrier();
  }

#pragma unroll
  for (int mi = 0; mi < 4; ++mi) {
    const int gr0 = mt * 128 + wm * 64 + mi * 16 + ((lane >> 4) << 2);
#pragma unroll
    for (int ni = 0; ni < 4; ++ni) {
      const int nc = nt * 128 + wn * 64 + ni * 16 + (lane & 15);
#pragma unroll
      for (int r = 0; r < 4; ++r) {
        const int gr = gr0 + r;
        if (gr < count) {
          const float g = accg[mi][ni][r];
          const float u = accu[mi][ni][r];
          const float h = g / (1.f + __expf(-g)) * u;
          H[(size_t)(base + gr) * N + nc] = f2bf(h);
        }
      }
    }
  }
}

// ---------------- GEMM2 (best measured config): A reg-staged, B async dbuf ----------------
__global__ __launch_bounds__(256, 2) void k_gemm2i(
    const ushort* __restrict__ Hr, const ushort* __restrict__ id_,
    const ushort* __restrict__ Hs, const ushort* __restrict__ isd,
    float* __restrict__ out, const int* __restrict__ offs,
    const int* __restrict__ ptok, const float* __restrict__ pw,
    const int* __restrict__ meta, const int* __restrict__ mtl) {
  const int swz = (blockIdx.x & 7) * G2_Q + (blockIdx.x >> 3);
  int mt, nt, base, count, K, KT;
  const ushort* Hbuf;
  const char* img;
  bool routed;
  if (swz < G2_SH) {
    mt = swz & 15; nt = swz >> 4;
    base = 0; count = TOKS; K = FS; KT = 44;
    Hbuf = Hs; img = (const char*)isd + (size_t)(nt * 44) * 16384;
    routed = false;
  } else {
    const int r = swz - G2_SH;
    const int n_mt = meta[0];
    if (r >= n_mt * 16) return;
    const int tile = mtl[r / 16];
    nt = r % 16;
    const int e = tile >> 8; mt = tile & 255;
    base = offs[e]; count = offs[e + 1] - base; K = FR; KT = 22;
    Hbuf = Hr; img = (const char*)id_ + (size_t)((e * 16 + nt) * 22) * 16384;
    routed = true;
  }

  __shared__ char smem[49152];  // A 16K | B buf0 16K | B buf1 16K
  const int tid = threadIdx.x, lane = tid & 63, wid = tid >> 6;
  const int wm = wid >> 1, wn = wid & 1;

  const int aj = tid & 7;
  const ushort* aptr[4];
  uint32_t alds[4];
#pragma unroll
  for (int i = 0; i < 4; ++i) {
    const int row = i * 32 + (tid >> 3);
    const int gr = mt * 128 + row;
    const int ar = base + (gr < count ? gr : count - 1);
    aptr[i] = Hbuf + (size_t)ar * K + aj * 8;
    alds[i] = (uint32_t)(row * 128 + ((aj ^ (row & 7)) * 16));
  }

  const f32x4 fz = {0.f, 0.f, 0.f, 0.f};
  f32x4 acc[4][4];
#pragma unroll
  for (int mi = 0; mi < 4; ++mi)
#pragma unroll
    for (int ni = 0; ni < 4; ++ni) acc[mi][ni] = fz;

  s16x8 areg[4];
#pragma unroll
  for (int i = 0; i < 4; ++i) areg[i] = *(const s16x8*)(aptr[i]);
#pragma unroll
  for (int i = 0; i < 4; ++i) {
    const int o = (i * 4 + wid) * 1024 + lane * 16;
    gload16(img + o, smem + 16384 + o);
  }

  for (int t = 0; t < KT; ++t) {
    const int bufo = 16384 + (t & 1) * 16384;
#pragma unroll
    for (int i = 0; i < 4; ++i) *(s16x8*)(smem + alds[i]) = areg[i];
    __builtin_amdgcn_sched_barrier(0);
    if (t + 1 < KT) {
#pragma unroll
      for (int i = 0; i < 4; ++i) areg[i] = *(const s16x8*)(aptr[i] + (t + 1) * 64);
      const int nbufo = 16384 + ((t + 1) & 1) * 16384;
      const char* gB = img + (size_t)(t + 1) * 16384;
#pragma unroll
      for (int i = 0; i < 4; ++i) {
        const int o = (i * 4 + wid) * 1024 + lane * 16;
        gload16(gB + o, smem + nbufo + o);
      }
      asm volatile("s_waitcnt vmcnt(8) lgkmcnt(0)" ::: "memory");
    } else {
      asm volatile("s_waitcnt vmcnt(0) lgkmcnt(0)" ::: "memory");
    }
    __builtin_amdgcn_sched_barrier(0);
    __builtin_amdgcn_s_barrier();
    __builtin_amdgcn_sched_barrier(0);
    __builtin_amdgcn_s_setprio(1);
#pragma unroll
    for (int kk = 0; kk < 64; kk += 32) {
      s16x8 af[4];
#pragma unroll
      for (int mi = 0; mi < 4; ++mi) {
        const int row = wm * 64 + mi * 16 + (lane & 15);
        const int slot = (kk >> 3) + (lane >> 4);
        af[mi] = *(const s16x8*)(smem + row * 128 + ((slot ^ (row & 7)) * 16));
      }
#pragma unroll
      for (int ni = 0; ni < 4; ++ni) {
        const int colg = wn * 64 + ni * 16 + (lane & 15);
        const int slot = (kk >> 3) + (lane >> 4);
        const uint32_t boff = (uint32_t)(colg * 128 + ((slot ^ (colg & 7)) * 16));
        const s16x8 bb = *(const s16x8*)(smem + bufo + boff);
#pragma unroll
        for (int mi = 0; mi < 4; ++mi)
          acc[mi][ni] = __builtin_amdgcn_mfma_f32_16x16x32_bf16(af[mi], bb, acc[mi][ni], 0, 0, 0);
      }
    }
    __builtin_amdgcn_s_setprio(0);
    __builtin_amdgcn_s_barrier();
  }

#pragma unroll
  for (int mi = 0; mi < 4; ++mi) {
    const int gr0 = mt * 128 + wm * 64 + mi * 16 + ((lane >> 4) << 2);
#pragma unroll
    for (int ni = 0; ni < 4; ++ni) {
      const int nc = nt * 128 + wn * 64 + ni * 16 + (lane & 15);
#pragma unroll
      for (int r = 0; r < 4; ++r) {
        const int gr = gr0 + r;
        if (gr < count) {
          const int arow = base + gr;
          const float s = routed ? (RSCALE * pw[arow]) : 1.f;
          const int tok = routed ? ptok[arow] : gr;
          unsafeAtomicAdd(out + (size_t)tok * DHID + nc, acc[mi][ni][r] * s);
        }
      }
    }
  }
}

extern "C" void kernel_launch(void* const* d_in, const int* in_sizes, int n_in,
                              void* d_out, int out_size, void* d_ws, size_t ws_size,
                              hipStream_t stream) {
  const float* x   = (const float*)d_in[0];
  const float* wr  = (const float*)d_in[1];
  const float* wg  = (const float*)d_in[2];
  const float* wu  = (const float*)d_in[3];
  const float* wd  = (const float*)d_in[4];
  const float* wsg = (const float*)d_in[5];
  const float* wsu = (const float*)d_in[6];
  const float* wsd = (const float*)d_in[7];
  float* out = (float*)d_out;

  uint8_t* p = (uint8_t*)d_ws;
  ushort* xb   = (ushort*)p; p += (size_t)TOKS * DHID * 2;
  int* top_e   = (int*)p;    p += (size_t)2 * TOKS * 4;
  float* top_w = (float*)p;  p += (size_t)2 * TOKS * 4;
  int* offs    = (int*)p;    p += 256;
  int* meta    = (int*)p;    p += 64;
  int* mtl     = (int*)p;    p += 256;
  int* ptok    = (int*)p;    p += (size_t)2 * TOKS * 4;
  float* pw    = (float*)p;  p += (size_t)2 * TOKS * 4;
  ushort* Hr   = (ushort*)p; p += (size_t)2 * TOKS * FR * 2;
  ushort* Hs   = (ushort*)p; p += (size_t)TOKS * FS * 2;
  ushort* ig   = (ushort*)p; p += (size_t)NIMG_WG * 8192 * 2;
  ushort* iu   = (ushort*)p; p += (size_t)NIMG_WG * 8192 * 2;
  ushort* id_  = (ushort*)p; p += (size_t)NIMG_WD * 8192 * 2;
  ushort* isg  = (ushort*)p; p += (size_t)NIMG_SG * 8192 * 2;
  ushort* isu  = (ushort*)p; p += (size_t)NIMG_SG * 8192 * 2;
  ushort* isd  = (ushort*)p; p += (size_t)NIMG_SD * 8192 * 2;

  hipMemsetAsync(d_out, 0, (size_t)out_size * sizeof(float), stream);
  k_rwimg<<<RW_GRID, 256, 0, stream>>>(x, wr, xb, top_e, top_w,
                                       wg, wu, wsg, wsu,
                                       ig, iu, isg, isu);
  k_lists<<<1, 256, 0, stream>>>(top_e, top_w, offs, ptok, pw, meta, mtl);
  k_gemm1i<<<G1_FULL, 256, 0, stream>>>(xb, ig, iu, Hr, isg, isu, Hs,
                                        offs, ptok, meta, mtl,
                                        wd, wsd, id_, isd);
  k_gemm2i<<<G2_GRID, 256, 0, stream>>>(Hr, id_, Hs, isd, out,
                                        offs, ptok, pw, meta, mtl);
}

// Round 21
// 361.580 us; speedup vs baseline: 1.0001x; 1.0001x over previous
//
#include <hip/hip_runtime.h>
#include <hip/hip_bf16.h>
#include <stdint.h>

#define TOKS 2048
#define DHID 2048
#define NEXP 8
#define FR 1408
#define FS 2816
#define RSCALE 2.5f

// gemm1: shared 16mt*22nt=352 first, routed <=39*11=429 -> 784=8*98
#define G1_SH 352
#define G1_GRID 784
#define G1_Q (G1_GRID / 8)
// gemm2 (BN=128): shared 16*16=256, routed <=39*16=624 -> 880=8*110
#define G2_SH 256
#define G2_GRID 880
#define G2_Q (G2_GRID / 8)
// weight image counts (64k x 128n panels of 16KB)
#define NIMG_WG 2816   // 8e * 11nt * 32kt
#define NIMG_WD 2816   // 8e * 16nt * 22kt
#define NIMG_SG 704    // 22nt * 32kt
#define NIMG_SD 704    // 16nt * 44kt
// rwimg converts only gate/up (down converts inside gemm1 dispatch)
#define RW_GRID (512 + NIMG_WG * 2 + NIMG_SG * 2)   // 7552
#define G1_CONV (NIMG_WD + NIMG_SD)                 // 3520
#define G1_FULL (G1_GRID + G1_CONV)                 // 4304

typedef float f32x4 __attribute__((ext_vector_type(4)));
typedef short s16x8 __attribute__((ext_vector_type(8)));

__device__ __forceinline__ ushort f2bf(float f) {
  union { __hip_bfloat16 b; ushort u; } v;
  v.b = __float2bfloat16(f);
  return v.u;
}

__device__ __forceinline__ void gload16(const void* g, void* l) {
  __builtin_amdgcn_global_load_lds(
      (const __attribute__((address_space(1))) unsigned int*)g,
      (__attribute__((address_space(3))) unsigned int*)l, 16, 0, 0);
}

// shared conversion body: one 64k x 128n panel fp32[K][N] -> swizzled bf16 image
__device__ __forceinline__ void conv_panel(
    const float* __restrict__ src, ushort* __restrict__ dst,
    int N, int nt, int kt, char* smem) {
  float (*lds)[133] = (float(*)[133])smem;
  const int tid = threadIdx.x;
#pragma unroll
  for (int j = 0; j < 8; ++j) {
    const int idx = j * 256 + tid;
    const int row = idx >> 5, c4 = (idx & 31) << 2;
    const float4 v = *(const float4*)(src + (size_t)(kt * 64 + row) * N + nt * 128 + c4);
    lds[row][c4] = v.x; lds[row][c4 + 1] = v.y; lds[row][c4 + 2] = v.z; lds[row][c4 + 3] = v.w;
  }
  __syncthreads();
#pragma unroll
  for (int s = 0; s < 4; ++s) {
    const int sid = s * 256 + tid;
    const int col = sid >> 3, ks = sid & 7;
    ushort tmp[8];
#pragma unroll
    for (int j = 0; j < 8; ++j) tmp[j] = f2bf(lds[ks * 8 + j][col]);
    *(s16x8*)((char*)dst + col * 128 + ((ks ^ (col & 7)) * 16)) = *(const s16x8*)&tmp[0];
  }
}

// ---------------- fused: router (blocks 0..511) + gate/up weight->image ----------------
__global__ __launch_bounds__(256) void k_rwimg(
    const float* __restrict__ x, const float* __restrict__ wr,
    ushort* __restrict__ xb, int* __restrict__ top_e, float* __restrict__ top_w,
    const float* __restrict__ wg, const float* __restrict__ wu,
    const float* __restrict__ wsg, const float* __restrict__ wsu,
    ushort* __restrict__ ig, ushort* __restrict__ iu,
    ushort* __restrict__ isg, ushort* __restrict__ isu) {
  __shared__ char smem[34048];
  if (blockIdx.x < 512) {
    const int wid = threadIdx.x >> 6, lane = threadIdx.x & 63;
    const int t = blockIdx.x * 4 + wid;
    const float* xrow = x + (size_t)t * DHID;
    float acc[NEXP];
#pragma unroll
    for (int e = 0; e < NEXP; ++e) acc[e] = 0.f;
#pragma unroll 4
    for (int j = 0; j < DHID / 64; ++j) {
      const int k = j * 64 + lane;
      const float xv = xrow[k];
      xb[(size_t)t * DHID + k] = f2bf(xv);
      const float4 w0 = *(const float4*)(wr + (size_t)k * 8);
      const float4 w1 = *(const float4*)(wr + (size_t)k * 8 + 4);
      acc[0] += xv * w0.x; acc[1] += xv * w0.y; acc[2] += xv * w0.z; acc[3] += xv * w0.w;
      acc[4] += xv * w1.x; acc[5] += xv * w1.y; acc[6] += xv * w1.z; acc[7] += xv * w1.w;
    }
#pragma unroll
    for (int e = 0; e < NEXP; ++e) {
#pragma unroll
      for (int off = 32; off; off >>= 1) acc[e] += __shfl_xor(acc[e], off);
    }
    if (lane == 0) {
      int i1 = 0;
#pragma unroll
      for (int e = 1; e < NEXP; ++e) if (acc[e] > acc[i1]) i1 = e;
      int i2 = (i1 == 0) ? 1 : 0;
#pragma unroll
      for (int e = 0; e < NEXP; ++e) if (e != i1 && acc[e] > acc[i2]) i2 = e;
      const float w1 = 1.f / (1.f + expf(acc[i2] - acc[i1]));
      top_e[2 * t] = i1; top_e[2 * t + 1] = i2;
      top_w[2 * t] = w1; top_w[2 * t + 1] = 1.f - w1;
    }
    return;
  }
  int id = blockIdx.x - 512;
  const float* src; ushort* dst; int N, ntT, ktT;
  if (id < NIMG_WG)                   { src = wg;  dst = ig;  N = FR; ntT = 11; ktT = 32; }
  else if ((id -= NIMG_WG) < NIMG_WG) { src = wu;  dst = iu;  N = FR; ntT = 11; ktT = 32; }
  else if ((id -= NIMG_WG) < NIMG_SG) { src = wsg; dst = isg; N = FS; ntT = 22; ktT = 32; }
  else { id -= NIMG_SG;                 src = wsu; dst = isu; N = FS; ntT = 22; ktT = 32; }
  const int per_e = ntT * ktT;
  const int e = id / per_e, rem = id % per_e;
  const int nt = rem / ktT, kt = rem % ktT;
  const int K = ktT * 64;
  conv_panel(src + (size_t)e * K * N, dst + (size_t)id * 8192, N, nt, kt, smem);
}

// ---------------- per-expert token lists + m-tile work list ----------------
__global__ __launch_bounds__(256) void k_lists(
    const int* __restrict__ top_e, const float* __restrict__ top_w,
    int* __restrict__ offs, int* __restrict__ ptok, float* __restrict__ pw,
    int* __restrict__ meta, int* __restrict__ mtl) {
  __shared__ int cnt[NEXP], fill[NEXP], loff[NEXP + 1];
  const int tid = threadIdx.x;
  if (tid < NEXP) { cnt[tid] = 0; fill[tid] = 0; }
  __syncthreads();
  for (int p = tid; p < 2 * TOKS; p += 256) atomicAdd(&cnt[top_e[p]], 1);
  __syncthreads();
  if (tid == 0) {
    loff[0] = 0;
    for (int e = 0; e < NEXP; ++e) loff[e + 1] = loff[e] + cnt[e];
    int n = 0;
    for (int e = 0; e < NEXP; ++e)
      for (int m = 0; m * 128 < cnt[e]; ++m) mtl[n++] = (e << 8) | m;
    meta[0] = n;
  }
  __syncthreads();
  for (int p = tid; p < 2 * TOKS; p += 256) {
    const int e = top_e[p];
    const int pos = loff[e] + atomicAdd(&fill[e], 1);
    ptok[pos] = p >> 1;
    pw[pos] = top_w[p];
  }
  if (tid < NEXP + 1) offs[tid] = loff[tid];
}

// ---------------- GEMM1 + trailing down-weight conversion blocks ----------------
__global__ __launch_bounds__(256, 2) void k_gemm1i(
    const ushort* __restrict__ xb,
    const ushort* __restrict__ ig, const ushort* __restrict__ iu, ushort* __restrict__ Hr,
    const ushort* __restrict__ isg, const ushort* __restrict__ isu, ushort* __restrict__ Hs,
    const int* __restrict__ offs, const int* __restrict__ ptok,
    const int* __restrict__ meta, const int* __restrict__ mtl,
    const float* __restrict__ wd, const float* __restrict__ wsd,
    ushort* __restrict__ id_, ushort* __restrict__ isd) {
  __shared__ char smem[81920];  // gemm1: A 16K | buf0 g+u 32K | buf1 g+u 32K; conv aliases front
  if (blockIdx.x >= G1_GRID) {
    int cid = blockIdx.x - G1_GRID;
    const float* src; ushort* dst; int ntT, ktT;
    if (cid < NIMG_WD) { src = wd; dst = id_; ntT = 16; ktT = 22; }
    else { cid -= NIMG_WD; src = wsd; dst = isd; ntT = 16; ktT = 44; }
    const int per_e = ntT * ktT;
    const int e = cid / per_e, rem = cid % per_e;
    const int nt = rem / ktT, kt = rem % ktT;
    const int K = ktT * 64;
    conv_panel(src + (size_t)e * K * DHID, dst + (size_t)cid * 8192, DHID, nt, kt, smem);
    return;
  }
  constexpr int KT = DHID / 64;
  const int swz = (blockIdx.x & 7) * G1_Q + (blockIdx.x >> 3);
  int mt, nt, N, base, count;
  const char *imgG, *imgU;
  ushort* H;
  bool gather;
  if (swz < G1_SH) {
    mt = swz & 15; nt = swz >> 4;
    base = 0; count = TOKS; N = FS;
    imgG = (const char*)isg + (size_t)(nt * 32) * 16384;
    imgU = (const char*)isu + (size_t)(nt * 32) * 16384;
    H = Hs; gather = false;
  } else {
    const int r = swz - G1_SH;
    const int n_mt = meta[0];
    if (r >= n_mt * 11) return;
    const int tile = mtl[r / 11];
    nt = r % 11;
    const int e = tile >> 8; mt = tile & 255;
    base = offs[e]; count = offs[e + 1] - base; N = FR;
    imgG = (const char*)ig + (size_t)((e * 11 + nt) * 32) * 16384;
    imgU = (const char*)iu + (size_t)((e * 11 + nt) * 32) * 16384;
    H = Hr; gather = true;
  }

  const int tid = threadIdx.x, lane = tid & 63, wid = tid >> 6;
  const int wm = wid >> 1, wn = wid & 1;

  const int aj = tid & 7;
  const ushort* aptr[4];
  uint32_t alds[4];
#pragma unroll
  for (int i = 0; i < 4; ++i) {
    const int row = i * 32 + (tid >> 3);
    const int gr = mt * 128 + row;
    const int arow = gather ? ptok[base + (gr < count ? gr : count - 1)] : gr;
    aptr[i] = xb + (size_t)arow * DHID + aj * 8;
    alds[i] = (uint32_t)(row * 128 + ((aj ^ (row & 7)) * 16));
  }

  const f32x4 fz = {0.f, 0.f, 0.f, 0.f};
  f32x4 accg[4][4], accu[4][4];
#pragma unroll
  for (int mi = 0; mi < 4; ++mi)
#pragma unroll
    for (int ni = 0; ni < 4; ++ni) { accg[mi][ni] = fz; accu[mi][ni] = fz; }

  s16x8 areg[4];
#pragma unroll
  for (int i = 0; i < 4; ++i) areg[i] = *(const s16x8*)(aptr[i]);
#pragma unroll
  for (int i = 0; i < 4; ++i) {
    const int o = (i * 4 + wid) * 1024 + lane * 16;
    gload16(imgG + o, smem + 16384 + o);
    gload16(imgU + o, smem + 32768 + o);
  }

  for (int t = 0; t < KT; ++t) {
    const int bufo = 16384 + (t & 1) * 32768;
#pragma unroll
    for (int i = 0; i < 4; ++i) *(s16x8*)(smem + alds[i]) = areg[i];
    __builtin_amdgcn_sched_barrier(0);
    if (t + 1 < KT) {
#pragma unroll
      for (int i = 0; i < 4; ++i) areg[i] = *(const s16x8*)(aptr[i] + (t + 1) * 64);
      const int nbufo = 16384 + ((t + 1) & 1) * 32768;
      const char* gG = imgG + (size_t)(t + 1) * 16384;
      const char* gU = imgU + (size_t)(t + 1) * 16384;
#pragma unroll
      for (int i = 0; i < 4; ++i) {
        const int o = (i * 4 + wid) * 1024 + lane * 16;
        gload16(gG + o, smem + nbufo + o);
        gload16(gU + o, smem + nbufo + 16384 + o);
      }
      asm volatile("s_waitcnt vmcnt(12) lgkmcnt(0)" ::: "memory");
    } else {
      asm volatile("s_waitcnt vmcnt(0) lgkmcnt(0)" ::: "memory");
    }
    __builtin_amdgcn_sched_barrier(0);
    __builtin_amdgcn_s_barrier();
    __builtin_amdgcn_sched_barrier(0);
    __builtin_amdgcn_s_setprio(1);
#pragma unroll
    for (int kk = 0; kk < 64; kk += 32) {
      s16x8 af[4];
#pragma unroll
      for (int mi = 0; mi < 4; ++mi) {
        const int row = wm * 64 + mi * 16 + (lane & 15);
        const int slot = (kk >> 3) + (lane >> 4);
        af[mi] = *(const s16x8*)(smem + row * 128 + ((slot ^ (row & 7)) * 16));
      }
#pragma unroll
      for (int ni = 0; ni < 4; ++ni) {
        const int colg = wn * 64 + ni * 16 + (lane & 15);
        const int slot = (kk >> 3) + (lane >> 4);
        const uint32_t boff = (uint32_t)(colg * 128 + ((slot ^ (colg & 7)) * 16));
        const s16x8 bg = *(const s16x8*)(smem + bufo + boff);
        const s16x8 bu = *(const s16x8*)(smem + bufo + 16384 + boff);
#pragma unroll
        for (int mi = 0; mi < 4; ++mi) {
          accg[mi][ni] = __builtin_amdgcn_mfma_f32_16x16x32_bf16(af[mi], bg, accg[mi][ni], 0, 0, 0);
          accu[mi][ni] = __builtin_amdgcn_mfma_f32_16x16x32_bf16(af[mi], bu, accu[mi][ni], 0, 0, 0);
        }
      }
    }
    __builtin_amdgcn_s_setprio(0);
    __builtin_amdgcn_s_barrier();
  }

#pragma unroll
  for (int mi = 0; mi < 4; ++mi) {
    const int gr0 = mt * 128 + wm * 64 + mi * 16 + ((lane >> 4) << 2);
#pragma unroll
    for (int ni = 0; ni < 4; ++ni) {
      const int nc = nt * 128 + wn * 64 + ni * 16 + (lane & 15);
#pragma unroll
      for (int r = 0; r < 4; ++r) {
        const int gr = gr0 + r;
        if (gr < count) {
          const float g = accg[mi][ni][r];
          const float u = accu[mi][ni][r];
          const float h = g / (1.f + __expf(-g)) * u;
          H[(size_t)(base + gr) * N + nc] = f2bf(h);
        }
      }
    }
  }
}

// ---------------- GEMM2 (best measured config): A reg-staged, B async dbuf ----------------
__global__ __launch_bounds__(256, 2) void k_gemm2i(
    const ushort* __restrict__ Hr, const ushort* __restrict__ id_,
    const ushort* __restrict__ Hs, const ushort* __restrict__ isd,
    float* __restrict__ out, const int* __restrict__ offs,
    const int* __restrict__ ptok, const float* __restrict__ pw,
    const int* __restrict__ meta, const int* __restrict__ mtl) {
  const int swz = (blockIdx.x & 7) * G2_Q + (blockIdx.x >> 3);
  int mt, nt, base, count, K, KT;
  const ushort* Hbuf;
  const char* img;
  bool routed;
  if (swz < G2_SH) {
    mt = swz & 15; nt = swz >> 4;
    base = 0; count = TOKS; K = FS; KT = 44;
    Hbuf = Hs; img = (const char*)isd + (size_t)(nt * 44) * 16384;
    routed = false;
  } else {
    const int r = swz - G2_SH;
    const int n_mt = meta[0];
    if (r >= n_mt * 16) return;
    const int tile = mtl[r / 16];
    nt = r % 16;
    const int e = tile >> 8; mt = tile & 255;
    base = offs[e]; count = offs[e + 1] - base; K = FR; KT = 22;
    Hbuf = Hr; img = (const char*)id_ + (size_t)((e * 16 + nt) * 22) * 16384;
    routed = true;
  }

  __shared__ char smem[49152];  // A 16K | B buf0 16K | B buf1 16K
  const int tid = threadIdx.x, lane = tid & 63, wid = tid >> 6;
  const int wm = wid >> 1, wn = wid & 1;

  const int aj = tid & 7;
  const ushort* aptr[4];
  uint32_t alds[4];
#pragma unroll
  for (int i = 0; i < 4; ++i) {
    const int row = i * 32 + (tid >> 3);
    const int gr = mt * 128 + row;
    const int ar = base + (gr < count ? gr : count - 1);
    aptr[i] = Hbuf + (size_t)ar * K + aj * 8;
    alds[i] = (uint32_t)(row * 128 + ((aj ^ (row & 7)) * 16));
  }

  const f32x4 fz = {0.f, 0.f, 0.f, 0.f};
  f32x4 acc[4][4];
#pragma unroll
  for (int mi = 0; mi < 4; ++mi)
#pragma unroll
    for (int ni = 0; ni < 4; ++ni) acc[mi][ni] = fz;

  s16x8 areg[4];
#pragma unroll
  for (int i = 0; i < 4; ++i) areg[i] = *(const s16x8*)(aptr[i]);
#pragma unroll
  for (int i = 0; i < 4; ++i) {
    const int o = (i * 4 + wid) * 1024 + lane * 16;
    gload16(img + o, smem + 16384 + o);
  }

  for (int t = 0; t < KT; ++t) {
    const int bufo = 16384 + (t & 1) * 16384;
#pragma unroll
    for (int i = 0; i < 4; ++i) *(s16x8*)(smem + alds[i]) = areg[i];
    __builtin_amdgcn_sched_barrier(0);
    if (t + 1 < KT) {
#pragma unroll
      for (int i = 0; i < 4; ++i) areg[i] = *(const s16x8*)(aptr[i] + (t + 1) * 64);
      const int nbufo = 16384 + ((t + 1) & 1) * 16384;
      const char* gB = img + (size_t)(t + 1) * 16384;
#pragma unroll
      for (int i = 0; i < 4; ++i) {
        const int o = (i * 4 + wid) * 1024 + lane * 16;
        gload16(gB + o, smem + nbufo + o);
      }
      asm volatile("s_waitcnt vmcnt(8) lgkmcnt(0)" ::: "memory");
    } else {
      asm volatile("s_waitcnt vmcnt(0) lgkmcnt(0)" ::: "memory");
    }
    __builtin_amdgcn_sched_barrier(0);
    __builtin_amdgcn_s_barrier();
    __builtin_amdgcn_sched_barrier(0);
    __builtin_amdgcn_s_setprio(1);
#pragma unroll
    for (int kk = 0; kk < 64; kk += 32) {
      s16x8 af[4];
#pragma unroll
      for (int mi = 0; mi < 4; ++mi) {
        const int row = wm * 64 + mi * 16 + (lane & 15);
        const int slot = (kk >> 3) + (lane >> 4);
        af[mi] = *(const s16x8*)(smem + row * 128 + ((slot ^ (row & 7)) * 16));
      }
#pragma unroll
      for (int ni = 0; ni < 4; ++ni) {
        const int colg = wn * 64 + ni * 16 + (lane & 15);
        const int slot = (kk >> 3) + (lane >> 4);
        const uint32_t boff = (uint32_t)(colg * 128 + ((slot ^ (colg & 7)) * 16));
        const s16x8 bb = *(const s16x8*)(smem + bufo + boff);
#pragma unroll
        for (int mi = 0; mi < 4; ++mi)
          acc[mi][ni] = __builtin_amdgcn_mfma_f32_16x16x32_bf16(af[mi], bb, acc[mi][ni], 0, 0, 0);
      }
    }
    __builtin_amdgcn_s_setprio(0);
    __builtin_amdgcn_s_barrier();
  }

#pragma unroll
  for (int mi = 0; mi < 4; ++mi) {
    const int gr0 = mt * 128 + wm * 64 + mi * 16 + ((lane >> 4) << 2);
#pragma unroll
    for (int ni = 0; ni < 4; ++ni) {
      const int nc = nt * 128 + wn * 64 + ni * 16 + (lane & 15);
#pragma unroll
      for (int r = 0; r < 4; ++r) {
        const int gr = gr0 + r;
        if (gr < count) {
          const int arow = base + gr;
          const float s = routed ? (RSCALE * pw[arow]) : 1.f;
          const int tok = routed ? ptok[arow] : gr;
          unsafeAtomicAdd(out + (size_t)tok * DHID + nc, acc[mi][ni][r] * s);
        }
      }
    }
  }
}

extern "C" void kernel_launch(void* const* d_in, const int* in_sizes, int n_in,
                              void* d_out, int out_size, void* d_ws, size_t ws_size,
                              hipStream_t stream) {
  const float* x   = (const float*)d_in[0];
  const float* wr  = (const float*)d_in[1];
  const float* wg  = (const float*)d_in[2];
  const float* wu  = (const float*)d_in[3];
  const float* wd  = (const float*)d_in[4];
  const float* wsg = (const float*)d_in[5];
  const float* wsu = (const float*)d_in[6];
  const float* wsd = (const float*)d_in[7];
  float* out = (float*)d_out;

  uint8_t* p = (uint8_t*)d_ws;
  ushort* xb   = (ushort*)p; p += (size_t)TOKS * DHID * 2;
  int* top_e   = (int*)p;    p += (size_t)2 * TOKS * 4;
  float* top_w = (float*)p;  p += (size_t)2 * TOKS * 4;
  int* offs    = (int*)p;    p += 256;
  int* meta    = (int*)p;    p += 64;
  int* mtl     = (int*)p;    p += 256;
  int* ptok    = (int*)p;    p += (size_t)2 * TOKS * 4;
  float* pw    = (float*)p;  p += (size_t)2 * TOKS * 4;
  ushort* Hr   = (ushort*)p; p += (size_t)2 * TOKS * FR * 2;
  ushort* Hs   = (ushort*)p; p += (size_t)TOKS * FS * 2;
  ushort* ig   = (ushort*)p; p += (size_t)NIMG_WG * 8192 * 2;
  ushort* iu   = (ushort*)p; p += (size_t)NIMG_WG * 8192 * 2;
  ushort* id_  = (ushort*)p; p += (size_t)NIMG_WD * 8192 * 2;
  ushort* isg  = (ushort*)p; p += (size_t)NIMG_SG * 8192 * 2;
  ushort* isu  = (ushort*)p; p += (size_t)NIMG_SG * 8192 * 2;
  ushort* isd  = (ushort*)p; p += (size_t)NIMG_SD * 8192 * 2;

  hipMemsetAsync(d_out, 0, (size_t)out_size * sizeof(float), stream);
  k_rwimg<<<RW_GRID, 256, 0, stream>>>(x, wr, xb, top_e, top_w,
                                       wg, wu, wsg, wsu,
                                       ig, iu, isg, isu);
  k_lists<<<1, 256, 0, stream>>>(top_e, top_w, offs, ptok, pw, meta, mtl);
  k_gemm1i<<<G1_FULL, 256, 0, stream>>>(xb, ig, iu, Hr, isg, isu, Hs,
                                        offs, ptok, meta, mtl,
                                        wd, wsd, id_, isd);
  k_gemm2i<<<G2_GRID, 256, 0, stream>>>(Hr, id_, Hs, isd, out,
                                        offs, ptok, pw, meta, mtl);
}

// Round 22
// 357.564 us; speedup vs baseline: 1.0113x; 1.0112x over previous
//
#include <hip/hip_runtime.h>
#include <hip/hip_bf16.h>
#include <stdint.h>

#define TOKS 2048
#define DHID 2048
#define NEXP 8
#define FR 1408
#define FS 2816
#define RSCALE 2.5f

// gemm1: shared 16mt*22nt=352 first, routed <=39*11=429 -> 784=8*98
#define G1_SH 352
#define G1_GRID 784
#define G1_Q (G1_GRID / 8)
// gemm2 (BN=128): shared 16*16=256, routed <=39*16=624 -> 880=8*110
#define G2_SH 256
#define G2_GRID 880
#define G2_Q (G2_GRID / 8)
// weight image counts (64k x 128n panels of 16KB)
#define NIMG_WG 2816   // 8e * 11nt * 32kt
#define NIMG_WD 2816   // 8e * 16nt * 22kt
#define NIMG_SG 704    // 22nt * 32kt
#define NIMG_SD 704    // 16nt * 44kt
// rwimg converts only gate/up (down converts inside gemm1 dispatch)
#define RW_GRID (512 + NIMG_WG * 2 + NIMG_SG * 2)   // 7552
#define G1_CONV (NIMG_WD + NIMG_SD)                 // 3520
#define G1_FULL (G1_GRID + G1_CONV)                 // 4304

typedef float f32x4 __attribute__((ext_vector_type(4)));
typedef short s16x8 __attribute__((ext_vector_type(8)));

__device__ __forceinline__ ushort f2bf(float f) {
  union { __hip_bfloat16 b; ushort u; } v;
  v.b = __float2bfloat16(f);
  return v.u;
}

__device__ __forceinline__ void gload16(const void* g, void* l) {
  __builtin_amdgcn_global_load_lds(
      (const __attribute__((address_space(1))) unsigned int*)g,
      (__attribute__((address_space(3))) unsigned int*)l, 16, 0, 0);
}

// shared conversion body: one 64k x 128n panel fp32[K][N] -> swizzled bf16 image
__device__ __forceinline__ void conv_panel(
    const float* __restrict__ src, ushort* __restrict__ dst,
    int N, int nt, int kt, char* smem) {
  float (*lds)[133] = (float(*)[133])smem;
  const int tid = threadIdx.x;
#pragma unroll
  for (int j = 0; j < 8; ++j) {
    const int idx = j * 256 + tid;
    const int row = idx >> 5, c4 = (idx & 31) << 2;
    const float4 v = *(const float4*)(src + (size_t)(kt * 64 + row) * N + nt * 128 + c4);
    lds[row][c4] = v.x; lds[row][c4 + 1] = v.y; lds[row][c4 + 2] = v.z; lds[row][c4 + 3] = v.w;
  }
  __syncthreads();
#pragma unroll
  for (int s = 0; s < 4; ++s) {
    const int sid = s * 256 + tid;
    const int col = sid >> 3, ks = sid & 7;
    ushort tmp[8];
#pragma unroll
    for (int j = 0; j < 8; ++j) tmp[j] = f2bf(lds[ks * 8 + j][col]);
    *(s16x8*)((char*)dst + col * 128 + ((ks ^ (col & 7)) * 16)) = *(const s16x8*)&tmp[0];
  }
}

// ---------------- fused: router (blocks 0..511) + gate/up weight->image ----------------
__global__ __launch_bounds__(256) void k_rwimg(
    const float* __restrict__ x, const float* __restrict__ wr,
    ushort* __restrict__ xb, int* __restrict__ top_e, float* __restrict__ top_w,
    const float* __restrict__ wg, const float* __restrict__ wu,
    const float* __restrict__ wsg, const float* __restrict__ wsu,
    ushort* __restrict__ ig, ushort* __restrict__ iu,
    ushort* __restrict__ isg, ushort* __restrict__ isu) {
  __shared__ char smem[34048];
  if (blockIdx.x < 512) {
    const int wid = threadIdx.x >> 6, lane = threadIdx.x & 63;
    const int t = blockIdx.x * 4 + wid;
    const float* xrow = x + (size_t)t * DHID;
    float acc[NEXP];
#pragma unroll
    for (int e = 0; e < NEXP; ++e) acc[e] = 0.f;
#pragma unroll 4
    for (int j = 0; j < DHID / 64; ++j) {
      const int k = j * 64 + lane;
      const float xv = xrow[k];
      xb[(size_t)t * DHID + k] = f2bf(xv);
      const float4 w0 = *(const float4*)(wr + (size_t)k * 8);
      const float4 w1 = *(const float4*)(wr + (size_t)k * 8 + 4);
      acc[0] += xv * w0.x; acc[1] += xv * w0.y; acc[2] += xv * w0.z; acc[3] += xv * w0.w;
      acc[4] += xv * w1.x; acc[5] += xv * w1.y; acc[6] += xv * w1.z; acc[7] += xv * w1.w;
    }
#pragma unroll
    for (int e = 0; e < NEXP; ++e) {
#pragma unroll
      for (int off = 32; off; off >>= 1) acc[e] += __shfl_xor(acc[e], off);
    }
    if (lane == 0) {
      int i1 = 0;
#pragma unroll
      for (int e = 1; e < NEXP; ++e) if (acc[e] > acc[i1]) i1 = e;
      int i2 = (i1 == 0) ? 1 : 0;
#pragma unroll
      for (int e = 0; e < NEXP; ++e) if (e != i1 && acc[e] > acc[i2]) i2 = e;
      const float w1 = 1.f / (1.f + expf(acc[i2] - acc[i1]));
      top_e[2 * t] = i1; top_e[2 * t + 1] = i2;
      top_w[2 * t] = w1; top_w[2 * t + 1] = 1.f - w1;
    }
    return;
  }
  int id = blockIdx.x - 512;
  const float* src; ushort* dst; int N, ntT, ktT;
  if (id < NIMG_WG)                   { src = wg;  dst = ig;  N = FR; ntT = 11; ktT = 32; }
  else if ((id -= NIMG_WG) < NIMG_WG) { src = wu;  dst = iu;  N = FR; ntT = 11; ktT = 32; }
  else if ((id -= NIMG_WG) < NIMG_SG) { src = wsg; dst = isg; N = FS; ntT = 22; ktT = 32; }
  else { id -= NIMG_SG;                 src = wsu; dst = isu; N = FS; ntT = 22; ktT = 32; }
  const int per_e = ntT * ktT;
  const int e = id / per_e, rem = id % per_e;
  const int nt = rem / ktT, kt = rem % ktT;
  const int K = ktT * 64;
  conv_panel(src + (size_t)e * K * N, dst + (size_t)id * 8192, N, nt, kt, smem);
}

// ---------------- per-expert token lists + m-tile work list ----------------
__global__ __launch_bounds__(256) void k_lists(
    const int* __restrict__ top_e, const float* __restrict__ top_w,
    int* __restrict__ offs, int* __restrict__ ptok, float* __restrict__ pw,
    int* __restrict__ meta, int* __restrict__ mtl) {
  __shared__ int cnt[NEXP], fill[NEXP], loff[NEXP + 1];
  const int tid = threadIdx.x;
  if (tid < NEXP) { cnt[tid] = 0; fill[tid] = 0; }
  __syncthreads();
  for (int p = tid; p < 2 * TOKS; p += 256) atomicAdd(&cnt[top_e[p]], 1);
  __syncthreads();
  if (tid == 0) {
    loff[0] = 0;
    for (int e = 0; e < NEXP; ++e) loff[e + 1] = loff[e] + cnt[e];
    int n = 0;
    for (int e = 0; e < NEXP; ++e)
      for (int m = 0; m * 128 < cnt[e]; ++m) mtl[n++] = (e << 8) | m;
    meta[0] = n;
  }
  __syncthreads();
  for (int p = tid; p < 2 * TOKS; p += 256) {
    const int e = top_e[p];
    const int pos = loff[e] + atomicAdd(&fill[e], 1);
    ptok[pos] = p >> 1;
    pw[pos] = top_w[p];
  }
  if (tid < NEXP + 1) offs[tid] = loff[tid];
}

// ---------------- GEMM1 + trailing down-weight conversion blocks ----------------
__global__ __launch_bounds__(256, 2) void k_gemm1i(
    const ushort* __restrict__ xb,
    const ushort* __restrict__ ig, const ushort* __restrict__ iu, ushort* __restrict__ Hr,
    const ushort* __restrict__ isg, const ushort* __restrict__ isu, ushort* __restrict__ Hs,
    const int* __restrict__ offs, const int* __restrict__ ptok,
    const int* __restrict__ meta, const int* __restrict__ mtl,
    const float* __restrict__ wd, const float* __restrict__ wsd,
    ushort* __restrict__ id_, ushort* __restrict__ isd) {
  __shared__ char smem[81920];  // gemm1: A 16K | buf0 g+u 32K | buf1 g+u 32K; conv aliases front
  if (blockIdx.x >= G1_GRID) {
    int cid = blockIdx.x - G1_GRID;
    const float* src; ushort* dst; int ntT, ktT;
    if (cid < NIMG_WD) { src = wd; dst = id_; ntT = 16; ktT = 22; }
    else { cid -= NIMG_WD; src = wsd; dst = isd; ntT = 16; ktT = 44; }
    const int per_e = ntT * ktT;
    const int e = cid / per_e, rem = cid % per_e;
    const int nt = rem / ktT, kt = rem % ktT;
    const int K = ktT * 64;
    conv_panel(src + (size_t)e * K * DHID, dst + (size_t)cid * 8192, DHID, nt, kt, smem);
    return;
  }
  constexpr int KT = DHID / 64;
  const int swz = (blockIdx.x & 7) * G1_Q + (blockIdx.x >> 3);
  int mt, nt, N, base, count;
  const char *imgG, *imgU;
  ushort* H;
  bool gather;
  if (swz < G1_SH) {
    mt = swz & 15; nt = swz >> 4;
    base = 0; count = TOKS; N = FS;
    imgG = (const char*)isg + (size_t)(nt * 32) * 16384;
    imgU = (const char*)isu + (size_t)(nt * 32) * 16384;
    H = Hs; gather = false;
  } else {
    const int r = swz - G1_SH;
    const int n_mt = meta[0];
    if (r >= n_mt * 11) return;
    const int tile = mtl[r / 11];
    nt = r % 11;
    const int e = tile >> 8; mt = tile & 255;
    base = offs[e]; count = offs[e + 1] - base; N = FR;
    imgG = (const char*)ig + (size_t)((e * 11 + nt) * 32) * 16384;
    imgU = (const char*)iu + (size_t)((e * 11 + nt) * 32) * 16384;
    H = Hr; gather = true;
  }

  const int tid = threadIdx.x, lane = tid & 63, wid = tid >> 6;
  const int wm = wid >> 1, wn = wid & 1;

  const int aj = tid & 7;
  const ushort* aptr[4];
  uint32_t alds[4];
#pragma unroll
  for (int i = 0; i < 4; ++i) {
    const int row = i * 32 + (tid >> 3);
    const int gr = mt * 128 + row;
    const int arow = gather ? ptok[base + (gr < count ? gr : count - 1)] : gr;
    aptr[i] = xb + (size_t)arow * DHID + aj * 8;
    alds[i] = (uint32_t)(row * 128 + ((aj ^ (row & 7)) * 16));
  }

  const f32x4 fz = {0.f, 0.f, 0.f, 0.f};
  f32x4 accg[4][4], accu[4][4];
#pragma unroll
  for (int mi = 0; mi < 4; ++mi)
#pragma unroll
    for (int ni = 0; ni < 4; ++ni) { accg[mi][ni] = fz; accu[mi][ni] = fz; }

  s16x8 areg[4];
#pragma unroll
  for (int i = 0; i < 4; ++i) areg[i] = *(const s16x8*)(aptr[i]);
#pragma unroll
  for (int i = 0; i < 4; ++i) {
    const int o = (i * 4 + wid) * 1024 + lane * 16;
    gload16(imgG + o, smem + 16384 + o);
    gload16(imgU + o, smem + 32768 + o);
  }

  for (int t = 0; t < KT; ++t) {
    const int bufo = 16384 + (t & 1) * 32768;
#pragma unroll
    for (int i = 0; i < 4; ++i) *(s16x8*)(smem + alds[i]) = areg[i];
    __builtin_amdgcn_sched_barrier(0);
    if (t + 1 < KT) {
#pragma unroll
      for (int i = 0; i < 4; ++i) areg[i] = *(const s16x8*)(aptr[i] + (t + 1) * 64);
      const int nbufo = 16384 + ((t + 1) & 1) * 32768;
      const char* gG = imgG + (size_t)(t + 1) * 16384;
      const char* gU = imgU + (size_t)(t + 1) * 16384;
#pragma unroll
      for (int i = 0; i < 4; ++i) {
        const int o = (i * 4 + wid) * 1024 + lane * 16;
        gload16(gG + o, smem + nbufo + o);
        gload16(gU + o, smem + nbufo + 16384 + o);
      }
      asm volatile("s_waitcnt vmcnt(12) lgkmcnt(0)" ::: "memory");
    } else {
      asm volatile("s_waitcnt vmcnt(0) lgkmcnt(0)" ::: "memory");
    }
    __builtin_amdgcn_sched_barrier(0);
    __builtin_amdgcn_s_barrier();
    __builtin_amdgcn_sched_barrier(0);
    __builtin_amdgcn_s_setprio(1);
#pragma unroll
    for (int kk = 0; kk < 64; kk += 32) {
      s16x8 af[4];
#pragma unroll
      for (int mi = 0; mi < 4; ++mi) {
        const int row = wm * 64 + mi * 16 + (lane & 15);
        const int slot = (kk >> 3) + (lane >> 4);
        af[mi] = *(const s16x8*)(smem + row * 128 + ((slot ^ (row & 7)) * 16));
      }
#pragma unroll
      for (int ni = 0; ni < 4; ++ni) {
        const int colg = wn * 64 + ni * 16 + (lane & 15);
        const int slot = (kk >> 3) + (lane >> 4);
        const uint32_t boff = (uint32_t)(colg * 128 + ((slot ^ (colg & 7)) * 16));
        const s16x8 bg = *(const s16x8*)(smem + bufo + boff);
        const s16x8 bu = *(const s16x8*)(smem + bufo + 16384 + boff);
#pragma unroll
        for (int mi = 0; mi < 4; ++mi) {
          accg[mi][ni] = __builtin_amdgcn_mfma_f32_16x16x32_bf16(af[mi], bg, accg[mi][ni], 0, 0, 0);
          accu[mi][ni] = __builtin_amdgcn_mfma_f32_16x16x32_bf16(af[mi], bu, accu[mi][ni], 0, 0, 0);
        }
      }
    }
    __builtin_amdgcn_s_setprio(0);
    __builtin_amdgcn_s_barrier();
  }

#pragma unroll
  for (int mi = 0; mi < 4; ++mi) {
    const int gr0 = mt * 128 + wm * 64 + mi * 16 + ((lane >> 4) << 2);
#pragma unroll
    for (int ni = 0; ni < 4; ++ni) {
      const int nc = nt * 128 + wn * 64 + ni * 16 + (lane & 15);
#pragma unroll
      for (int r = 0; r < 4; ++r) {
        const int gr = gr0 + r;
        if (gr < count) {
          const float g = accg[mi][ni][r];
          const float u = accu[mi][ni][r];
          const float h = g / (1.f + __expf(-g)) * u;
          H[(size_t)(base + gr) * N + nc] = f2bf(h);
        }
      }
    }
  }
}

// ---------------- GEMM2 (best measured config): A reg-staged, B async dbuf ----------------
__global__ __launch_bounds__(256, 2) void k_gemm2i(
    const ushort* __restrict__ Hr, const ushort* __restrict__ id_,
    const ushort* __restrict__ Hs, const ushort* __restrict__ isd,
    float* __restrict__ out, const int* __restrict__ offs,
    const int* __restrict__ ptok, const float* __restrict__ pw,
    const int* __restrict__ meta, const int* __restrict__ mtl) {
  const int swz = (blockIdx.x & 7) * G2_Q + (blockIdx.x >> 3);
  int mt, nt, base, count, K, KT;
  const ushort* Hbuf;
  const char* img;
  bool routed;
  if (swz < G2_SH) {
    mt = swz & 15; nt = swz >> 4;
    base = 0; count = TOKS; K = FS; KT = 44;
    Hbuf = Hs; img = (const char*)isd + (size_t)(nt * 44) * 16384;
    routed = false;
  } else {
    const int r = swz - G2_SH;
    const int n_mt = meta[0];
    if (r >= n_mt * 16) return;
    const int tile = mtl[r / 16];
    nt = r % 16;
    const int e = tile >> 8; mt = tile & 255;
    base = offs[e]; count = offs[e + 1] - base; K = FR; KT = 22;
    Hbuf = Hr; img = (const char*)id_ + (size_t)((e * 16 + nt) * 22) * 16384;
    routed = true;
  }

  __shared__ char smem[49152];  // A 16K | B buf0 16K | B buf1 16K
  const int tid = threadIdx.x, lane = tid & 63, wid = tid >> 6;
  const int wm = wid >> 1, wn = wid & 1;

  const int aj = tid & 7;
  const ushort* aptr[4];
  uint32_t alds[4];
#pragma unroll
  for (int i = 0; i < 4; ++i) {
    const int row = i * 32 + (tid >> 3);
    const int gr = mt * 128 + row;
    const int ar = base + (gr < count ? gr : count - 1);
    aptr[i] = Hbuf + (size_t)ar * K + aj * 8;
    alds[i] = (uint32_t)(row * 128 + ((aj ^ (row & 7)) * 16));
  }

  const f32x4 fz = {0.f, 0.f, 0.f, 0.f};
  f32x4 acc[4][4];
#pragma unroll
  for (int mi = 0; mi < 4; ++mi)
#pragma unroll
    for (int ni = 0; ni < 4; ++ni) acc[mi][ni] = fz;

  s16x8 areg[4];
#pragma unroll
  for (int i = 0; i < 4; ++i) areg[i] = *(const s16x8*)(aptr[i]);
#pragma unroll
  for (int i = 0; i < 4; ++i) {
    const int o = (i * 4 + wid) * 1024 + lane * 16;
    gload16(img + o, smem + 16384 + o);
  }

  for (int t = 0; t < KT; ++t) {
    const int bufo = 16384 + (t & 1) * 16384;
#pragma unroll
    for (int i = 0; i < 4; ++i) *(s16x8*)(smem + alds[i]) = areg[i];
    __builtin_amdgcn_sched_barrier(0);
    if (t + 1 < KT) {
#pragma unroll
      for (int i = 0; i < 4; ++i) areg[i] = *(const s16x8*)(aptr[i] + (t + 1) * 64);
      const int nbufo = 16384 + ((t + 1) & 1) * 16384;
      const char* gB = img + (size_t)(t + 1) * 16384;
#pragma unroll
      for (int i = 0; i < 4; ++i) {
        const int o = (i * 4 + wid) * 1024 + lane * 16;
        gload16(gB + o, smem + nbufo + o);
      }
      asm volatile("s_waitcnt vmcnt(8) lgkmcnt(0)" ::: "memory");
    } else {
      asm volatile("s_waitcnt vmcnt(0) lgkmcnt(0)" ::: "memory");
    }
    __builtin_amdgcn_sched_barrier(0);
    __builtin_amdgcn_s_barrier();
    __builtin_amdgcn_sched_barrier(0);
    __builtin_amdgcn_s_setprio(1);
#pragma unroll
    for (int kk = 0; kk < 64; kk += 32) {
      s16x8 af[4];
#pragma unroll
      for (int mi = 0; mi < 4; ++mi) {
        const int row = wm * 64 + mi * 16 + (lane & 15);
        const int slot = (kk >> 3) + (lane >> 4);
        af[mi] = *(const s16x8*)(smem + row * 128 + ((slot ^ (row & 7)) * 16));
      }
#pragma unroll
      for (int ni = 0; ni < 4; ++ni) {
        const int colg = wn * 64 + ni * 16 + (lane & 15);
        const int slot = (kk >> 3) + (lane >> 4);
        const uint32_t boff = (uint32_t)(colg * 128 + ((slot ^ (colg & 7)) * 16));
        const s16x8 bb = *(const s16x8*)(smem + bufo + boff);
#pragma unroll
        for (int mi = 0; mi < 4; ++mi)
          acc[mi][ni] = __builtin_amdgcn_mfma_f32_16x16x32_bf16(af[mi], bb, acc[mi][ni], 0, 0, 0);
      }
    }
    __builtin_amdgcn_s_setprio(0);
    __builtin_amdgcn_s_barrier();
  }

#pragma unroll
  for (int mi = 0; mi < 4; ++mi) {
    const int gr0 = mt * 128 + wm * 64 + mi * 16 + ((lane >> 4) << 2);
#pragma unroll
    for (int ni = 0; ni < 4; ++ni) {
      const int nc = nt * 128 + wn * 64 + ni * 16 + (lane & 15);
#pragma unroll
      for (int r = 0; r < 4; ++r) {
        const int gr = gr0 + r;
        if (gr < count) {
          const int arow = base + gr;
          const float s = routed ? (RSCALE * pw[arow]) : 1.f;
          const int tok = routed ? ptok[arow] : gr;
          unsafeAtomicAdd(out + (size_t)tok * DHID + nc, acc[mi][ni][r] * s);
        }
      }
    }
  }
}

extern "C" void kernel_launch(void* const* d_in, const int* in_sizes, int n_in,
                              void* d_out, int out_size, void* d_ws, size_t ws_size,
                              hipStream_t stream) {
  const float* x   = (const float*)d_in[0];
  const float* wr  = (const float*)d_in[1];
  const float* wg  = (const float*)d_in[2];
  const float* wu  = (const float*)d_in[3];
  const float* wd  = (const float*)d_in[4];
  const float* wsg = (const float*)d_in[5];
  const float* wsu = (const float*)d_in[6];
  const float* wsd = (const float*)d_in[7];
  float* out = (float*)d_out;

  uint8_t* p = (uint8_t*)d_ws;
  ushort* xb   = (ushort*)p; p += (size_t)TOKS * DHID * 2;
  int* top_e   = (int*)p;    p += (size_t)2 * TOKS * 4;
  float* top_w = (float*)p;  p += (size_t)2 * TOKS * 4;
  int* offs    = (int*)p;    p += 256;
  int* meta    = (int*)p;    p += 64;
  int* mtl     = (int*)p;    p += 256;
  int* ptok    = (int*)p;    p += (size_t)2 * TOKS * 4;
  float* pw    = (float*)p;  p += (size_t)2 * TOKS * 4;
  ushort* Hr   = (ushort*)p; p += (size_t)2 * TOKS * FR * 2;
  ushort* Hs   = (ushort*)p; p += (size_t)TOKS * FS * 2;
  ushort* ig   = (ushort*)p; p += (size_t)NIMG_WG * 8192 * 2;
  ushort* iu   = (ushort*)p; p += (size_t)NIMG_WG * 8192 * 2;
  ushort* id_  = (ushort*)p; p += (size_t)NIMG_WD * 8192 * 2;
  ushort* isg  = (ushort*)p; p += (size_t)NIMG_SG * 8192 * 2;
  ushort* isu  = (ushort*)p; p += (size_t)NIMG_SG * 8192 * 2;
  ushort* isd  = (ushort*)p; p += (size_t)NIMG_SD * 8192 * 2;

  hipMemsetAsync(d_out, 0, (size_t)out_size * sizeof(float), stream);
  k_rwimg<<<RW_GRID, 256, 0, stream>>>(x, wr, xb, top_e, top_w,
                                       wg, wu, wsg, wsu,
                                       ig, iu, isg, isu);
  k_lists<<<1, 256, 0, stream>>>(top_e, top_w, offs, ptok, pw, meta, mtl);
  k_gemm1i<<<G1_FULL, 256, 0, stream>>>(xb, ig, iu, Hr, isg, isu, Hs,
                                        offs, ptok, meta, mtl,
                                        wd, wsd, id_, isd);
  k_gemm2i<<<G2_GRID, 256, 0, stream>>>(Hr, id_, Hs, isd, out,
                                        offs, ptok, pw, meta, mtl);
}